// Round 6
// baseline (195.501 us; speedup 1.0000x reference)
//
#include <hip/hip_runtime.h>
#include <math.h>

#define B_SZ 4
#define LQ_SZ 2048
#define C_SZ 256
#define NH_SZ 8
#define NL_SZ 4
#define NP_SZ 8
#define HD_SZ 32
#define LV_SZ 21760
#define NQ_SZ (B_SZ * LQ_SZ)   // 8192
#define MV_SZ (B_SZ * LV_SZ)   // 87040

typedef __attribute__((ext_vector_type(8))) short bf16x8;
typedef __attribute__((ext_vector_type(8))) unsigned short ushort8;
typedef __attribute__((ext_vector_type(4))) float f32x4;

__device__ __forceinline__ float bf2f(unsigned short u) {
  union { float f; unsigned v; } x;
  x.v = ((unsigned)u) << 16;
  return x.f;
}
__device__ __forceinline__ unsigned short f2bf(float f) {
  union { float f; unsigned v; } x;
  x.f = f;
  unsigned r = x.v + 0x7fffu + ((x.v >> 16) & 1u);
  return (unsigned short)(r >> 16);
}

// ---------------------------------------------------------------------------
// One-off weight preps (all tiny)
// ---------------------------------------------------------------------------
__global__ void convert_wt(const float* __restrict__ W,
                           unsigned short* __restrict__ Wt) {
  const int n = blockIdx.x, k = threadIdx.x;   // W is (256,256)
  Wt[n * 256 + k] = f2bf(W[k * 256 + n]);
}

// wcat[n][k], n<512: W_off, n<768: W_attn, n<896: Wa1, else 0
__global__ void build_wcat(const float* __restrict__ W_off,
                           const float* __restrict__ W_attn,
                           const float* __restrict__ Wa1,
                           unsigned short* __restrict__ wcat) {
  const int n = blockIdx.x, k = threadIdx.x;
  float v;
  if (n < 512) v = W_off[k * 512 + n];
  else if (n < 768) v = W_attn[k * 256 + (n - 512)];
  else if (n < 896) v = Wa1[k * 128 + (n - 768)];
  else v = 0.f;
  wcat[n * 256 + k] = f2bf(v);
}

__global__ void build_bcat(const float* __restrict__ b_off,
                           const float* __restrict__ b_attn,
                           const float* __restrict__ ba1,
                           float* __restrict__ bcat) {
  const int idx = blockIdx.x * 256 + threadIdx.x;
  float v;
  if (idx < 512) v = b_off[idx];
  else if (idx < 768) v = b_attn[idx - 512];
  else if (idx < 896) v = ba1[idx - 768];
  else v = 0.f;
  bcat[idx] = v;
}

// wa2t[n][k] = bf16(Wa2[k][n]), Wa2 is (128,512)
__global__ void build_wa2t(const float* __restrict__ Wa2,
                           unsigned short* __restrict__ wa2t) {
  const int n = blockIdx.x, k = threadIdx.x;
  wa2t[n * 128 + k] = f2bf(Wa2[k * 512 + n]);
}

// ---------------------------------------------------------------------------
// Barrier-free, LDS-free MFMA GEMM: C[M,n_total] = A[M,K_DIM] @ Wt^T + bias
// Wt pre-transposed bf16: Wt[n][K_DIM]. Block = 256 threads = 4 waves, each
// wave owns a 64(row) x 64(col) output; block tile 64 x 256 (grid.y tiles N).
// Each lane loads its MFMA fragments DIRECTLY from global (A: 2xfloat4 ->
// in-reg bf16 convert; B: 16B from L2-resident weights). No __syncthreads.
// MODE: 0 = f32 out, 1 = bf16 out,
//       2 = proj-special: col<768 -> f32 Cout; 768..895 -> relu bf16 to aux.
// ---------------------------------------------------------------------------
template <int MODE, int A_BF16, int K_DIM>
__global__ __launch_bounds__(256, 4) void gemm_direct(
    const void* __restrict__ Ain, const unsigned short* __restrict__ Wt,
    const float* __restrict__ bias, void* __restrict__ Cout,
    unsigned short* __restrict__ aux, int n_total) {
  constexpr int KSTEPS = K_DIM / 32;
  const int tid = threadIdx.x;
  const int lane = tid & 63;
  const int wc = (tid >> 6) & 3;   // wave's 64-col slice
  const long bm = (long)blockIdx.x * 64;
  const int bn0 = blockIdx.y * 256;
  const int rowc = lane & 15;      // 0..15
  const int rowg = lane >> 4;      // 0..3

  f32x4 acc[4][4];
#pragma unroll
  for (int m = 0; m < 4; ++m)
#pragma unroll
    for (int n = 0; n < 4; ++n) acc[m][n] = (f32x4){0.f, 0.f, 0.f, 0.f};

  const float* af32 = (const float*)Ain;
  const unsigned short* ab16 = (const unsigned short*)Ain;

#pragma unroll
  for (int ks = 0; ks < KSTEPS; ++ks) {
    bf16x8 afrag[4], bfrag[4];
#pragma unroll
    for (int m = 0; m < 4; ++m) {
      const long row = bm + m * 16 + rowc;
      if constexpr (A_BF16) {
        afrag[m] = *(const bf16x8*)(ab16 + row * K_DIM + ks * 32 + rowg * 8);
      } else {
        const float* ap = af32 + row * K_DIM + ks * 32 + rowg * 8;
        const float4 f0 = *(const float4*)ap;
        const float4 f1 = *(const float4*)(ap + 4);
        ushort8 u;
        u[0] = f2bf(f0.x); u[1] = f2bf(f0.y);
        u[2] = f2bf(f0.z); u[3] = f2bf(f0.w);
        u[4] = f2bf(f1.x); u[5] = f2bf(f1.y);
        u[6] = f2bf(f1.z); u[7] = f2bf(f1.w);
        union { ushort8 u8; bf16x8 b8; } cv;
        cv.u8 = u;
        afrag[m] = cv.b8;
      }
      bfrag[m] = *(const bf16x8*)(
          Wt + (long)(bn0 + wc * 64 + m * 16 + rowc) * K_DIM + ks * 32 +
          rowg * 8);
    }
#pragma unroll
    for (int m = 0; m < 4; ++m)
#pragma unroll
      for (int n = 0; n < 4; ++n)
        acc[m][n] = __builtin_amdgcn_mfma_f32_16x16x32_bf16(
            afrag[m], bfrag[n], acc[m][n], 0, 0, 0);
  }

  // epilogue
#pragma unroll
  for (int m = 0; m < 4; ++m) {
#pragma unroll
    for (int n = 0; n < 4; ++n) {
      const int col = bn0 + wc * 64 + n * 16 + rowc;
      const float bb = bias[col];
#pragma unroll
      for (int j = 0; j < 4; ++j) {
        const long row = bm + m * 16 + rowg * 4 + j;
        const float val = acc[m][n][j] + bb;
        if constexpr (MODE == 0) {
          ((float*)Cout)[row * n_total + col] = val;
        } else if constexpr (MODE == 1) {
          ((unsigned short*)Cout)[row * n_total + col] = f2bf(val);
        } else {
          if (col < 768) {
            ((float*)Cout)[row * n_total + col] = val;
          } else if (col < 896) {
            aux[row * 128 + (col - 768)] = f2bf(fmaxf(val, 0.f));
          }
        }
      }
    }
  }
}

// ---------------------------------------------------------------------------
// finalize: grid coords + softmax attention weights.
// One block = 16 queries, 256 threads.
// ---------------------------------------------------------------------------
__global__ __launch_bounds__(256) void finalize_qproj(
    const float* __restrict__ proj, const float* __restrict__ off2,
    const float* __restrict__ refpts, float* __restrict__ grid_out,
    float* __restrict__ aw_out) {
  const int tid = threadIdx.x;
  const long q0 = (long)blockIdx.x * 16;
#pragma unroll 4
  for (int q = 0; q < 16; ++q) {
    const long qi = q0 + q;
    const float* pr = proj + qi * 1024;
    // softmax over 32-sample groups (one head per 32 lanes)
    float logit = pr[512 + tid];
    float m = logit;
#pragma unroll
    for (int mask = 16; mask > 0; mask >>= 1)
      m = fmaxf(m, __shfl_xor(m, mask));
    float e = __expf(logit - m);
    float s = e;
#pragma unroll
    for (int mask = 16; mask > 0; mask >>= 1) s += __shfl_xor(s, mask);
    aw_out[qi * 256 + tid] = e / s;
    // sampling grid
#pragma unroll
    for (int half = 0; half < 2; ++half) {
      const int o = tid + half * 256;
      const float offv = pr[o] + 0.1f * off2[qi * 512 + o];
      const int l = (o >> 4) & 3;
      const int c = o & 1;
      const float rnorm = 1.f / (float)(128 >> l);
      const float ref = refpts[qi * 8 + l * 2 + c];
      grid_out[qi * 512 + o] = (ref + offv * rnorm) * 2.f - 1.f;
    }
  }
}

// ---------------------------------------------------------------------------
// Bilinear sampling + attention-weighted accumulation. v is bf16.
// Block = 2 queries, 256 threads.
// Phase 1: 512 samples -> corner byte-offsets + fused weights in LDS.
// Phase 2: thread = (query, head, channel-pair); 32 samples x 4 corners,
//          ushort2 loads (2 channels), broadcast LDS reads.
// ---------------------------------------------------------------------------
__global__ __launch_bounds__(256) void sample_kernel(
    const unsigned short* __restrict__ v, const float* __restrict__ grid,
    const float* __restrict__ aw, float* __restrict__ acc_out) {
  __shared__ int4 sidx[512];
  __shared__ float4 sw[512];
  const int tid = threadIdx.x;
  const long q0 = (long)blockIdx.x * 2;
  const int b = (int)(q0 >> 11);
  constexpr int starts[4] = {0, 16384, 20480, 21504};

  // ---- phase 1: per-sample corner offsets + weights ----
#pragma unroll
  for (int ss = 0; ss < 2; ++ss) {
    const int s = tid + ss * 256;
    const int qq = s >> 8, j = s & 255;       // j = h*32 + l*8 + p
    const int l = (j >> 3) & 3;
    const int HW = 128 >> l;
    const float fHW = (float)HW;
    const float2 g = *(const float2*)(grid + (q0 + qq) * 512 + 2 * j);
    const float w = aw[(q0 + qq) * 256 + j];
    const float x = ((g.x + 1.f) * fHW - 1.f) * 0.5f;
    const float y = ((g.y + 1.f) * fHW - 1.f) * 0.5f;
    const float x0f = floorf(x), y0f = floorf(y);
    const float lx = x - x0f, ly = y - y0f;
    const int ix0 = (int)x0f, iy0 = (int)y0f;
    const int ix1 = ix0 + 1, iy1 = iy0 + 1;
    const float vx0 = (ix0 >= 0 && ix0 < HW) ? 1.f : 0.f;
    const float vx1 = (ix1 >= 0 && ix1 < HW) ? 1.f : 0.f;
    const float vy0 = (iy0 >= 0 && iy0 < HW) ? 1.f : 0.f;
    const float vy1 = (iy1 >= 0 && iy1 < HW) ? 1.f : 0.f;
    const int cx0 = min(max(ix0, 0), HW - 1);
    const int cx1 = min(max(ix1, 0), HW - 1);
    const int cy0 = min(max(iy0, 0), HW - 1);
    const int cy1 = min(max(iy1, 0), HW - 1);
    const int base = starts[l];
    int4 o;  // byte offsets into v (256 ch * 2 B per location)
    o.x = (base + cy0 * HW + cx0) * 512;
    o.y = (base + cy0 * HW + cx1) * 512;
    o.z = (base + cy1 * HW + cx0) * 512;
    o.w = (base + cy1 * HW + cx1) * 512;
    sidx[s] = o;
    float4 wv;
    wv.x = (1.f - lx) * (1.f - ly) * vx0 * vy0 * w;
    wv.y = lx * (1.f - ly) * vx1 * vy0 * w;
    wv.z = (1.f - lx) * ly * vx0 * vy1 * w;
    wv.w = lx * ly * vx1 * vy1 * w;
    sw[s] = wv;
  }
  __syncthreads();

  // ---- phase 2: gather + weighted accumulate, 2 channels/thread ----
  const int qq = tid >> 7, h = (tid >> 4) & 7, dp = tid & 15;
  const char* vb =
      (const char*)v + ((long)b * LV_SZ * 256 + h * 32 + dp * 2) * 2;
  const int sbase = qq * 256 + h * 32;
  float acc0 = 0.f, acc1 = 0.f;
#pragma unroll 8
  for (int j = 0; j < 32; ++j) {
    const int4 o = sidx[sbase + j];
    const float4 w = sw[sbase + j];
    const ushort2 u0 = *(const ushort2*)(vb + o.x);
    const ushort2 u1 = *(const ushort2*)(vb + o.y);
    const ushort2 u2 = *(const ushort2*)(vb + o.z);
    const ushort2 u3 = *(const ushort2*)(vb + o.w);
    acc0 = fmaf(bf2f(u0.x), w.x, acc0);
    acc1 = fmaf(bf2f(u0.y), w.x, acc1);
    acc0 = fmaf(bf2f(u1.x), w.y, acc0);
    acc1 = fmaf(bf2f(u1.y), w.y, acc1);
    acc0 = fmaf(bf2f(u2.x), w.z, acc0);
    acc1 = fmaf(bf2f(u2.y), w.z, acc1);
    acc0 = fmaf(bf2f(u3.x), w.w, acc0);
    acc1 = fmaf(bf2f(u3.y), w.w, acc1);
  }
  float2 res = {acc0, acc1};
  *(float2*)(acc_out + (q0 + qq) * 256 + h * 32 + dp * 2) = res;
}

// ---------------------------------------------------------------------------
extern "C" void kernel_launch(void* const* d_in, const int* in_sizes, int n_in,
                              void* d_out, int out_size, void* d_ws,
                              size_t ws_size, hipStream_t stream) {
  const float* query  = (const float*)d_in[0];
  const float* refpts = (const float*)d_in[1];
  const float* value  = (const float*)d_in[2];
  const float* W_off  = (const float*)d_in[5];
  const float* b_off  = (const float*)d_in[6];
  const float* W_attn = (const float*)d_in[7];
  const float* b_attn = (const float*)d_in[8];
  const float* Wa1    = (const float*)d_in[9];
  const float* ba1    = (const float*)d_in[10];
  const float* Wa2    = (const float*)d_in[11];
  const float* ba2    = (const float*)d_in[12];
  const float* Wv     = (const float*)d_in[13];
  const float* bv     = (const float*)d_in[14];
  const float* Wo     = (const float*)d_in[15];
  const float* bo     = (const float*)d_in[16];
  float* out = (float*)d_out;

  char* ws = (char*)d_ws;
  // layout (total 122,556,416 B):
  unsigned short* v_ws = (unsigned short*)ws;                   // 44,564,480
  float* proj_ws = (float*)(ws + 44564480);                     // 33,554,432
  float* acc_ws  = (float*)(ws + 44564480);        // aliases proj (dead then)
  float* off2_ws = (float*)(ws + 78118912);                     // 16,777,216
  unsigned short* wcat_ws = (unsigned short*)(ws + 78118912);   // aliases off2
  unsigned short* hidb_ws = (unsigned short*)(ws + 94896128);   //  2,097,152
  float* grid_ws = (float*)(ws + 96993280);                     // 16,777,216
  float* aw_ws   = (float*)(ws + 113770496);                    //  8,388,608
  unsigned short* wtv_ws  = (unsigned short*)(ws + 122159104);  //    131,072
  unsigned short* wto_ws  = (unsigned short*)(ws + 122290176);  //    131,072
  unsigned short* wa2t_ws = (unsigned short*)(ws + 122421248);  //    131,072
  float* bcat_ws = (float*)(ws + 122552320);                    //      4,096

  // 0) weight preps
  convert_wt<<<256, 256, 0, stream>>>(Wv, wtv_ws);
  convert_wt<<<256, 256, 0, stream>>>(Wo, wto_ws);
  build_wcat<<<1024, 256, 0, stream>>>(W_off, W_attn, Wa1, wcat_ws);
  build_bcat<<<4, 256, 0, stream>>>(b_off, b_attn, ba1, bcat_ws);
  build_wa2t<<<512, 128, 0, stream>>>(Wa2, wa2t_ws);
  // 1) v = value @ Wv + bv  (bf16 out)
  gemm_direct<1, 0, 256><<<dim3(MV_SZ / 64, 1), 256, 0, stream>>>(
      value, wtv_ws, bv, v_ws, nullptr, 256);
  // 2) proj = query @ [W_off|W_attn|Wa1|0] + bcat; fused relu->hidb
  gemm_direct<2, 0, 256><<<dim3(NQ_SZ / 64, 4), 256, 0, stream>>>(
      query, wcat_ws, bcat_ws, proj_ws, hidb_ws, 1024);
  // 3) off2 = hidb @ Wa2 + ba2
  gemm_direct<0, 1, 128><<<dim3(NQ_SZ / 64, 2), 256, 0, stream>>>(
      hidb_ws, wa2t_ws, ba2, off2_ws, nullptr, 512);
  // 4) grids + attention weights
  finalize_qproj<<<NQ_SZ / 16, 256, 0, stream>>>(proj_ws, off2_ws, refpts,
                                                 grid_ws, aw_ws);
  // 5) bilinear sampling + weighted accumulation
  sample_kernel<<<NQ_SZ / 2, 256, 0, stream>>>(v_ws, grid_ws, aw_ws, acc_ws);
  // 6) out = acc @ Wo + bo
  gemm_direct<0, 0, 256><<<dim3(NQ_SZ / 64, 1), 256, 0, stream>>>(
      acc_ws, wto_ws, bo, out, nullptr, 256);
}

// Round 7
// 156.403 us; speedup vs baseline: 1.2500x; 1.2500x over previous
//
#include <hip/hip_runtime.h>
#include <math.h>

#define B_SZ 4
#define LQ_SZ 2048
#define C_SZ 256
#define NH_SZ 8
#define NL_SZ 4
#define NP_SZ 8
#define HD_SZ 32
#define LV_SZ 21760
#define NQ_SZ (B_SZ * LQ_SZ)   // 8192
#define MV_SZ (B_SZ * LV_SZ)   // 87040

typedef __attribute__((ext_vector_type(8))) short bf16x8;
typedef __attribute__((ext_vector_type(8))) unsigned short ushort8;
typedef __attribute__((ext_vector_type(4))) float f32x4;

__device__ __forceinline__ float bf2f(unsigned short u) {
  union { float f; unsigned v; } x;
  x.v = ((unsigned)u) << 16;
  return x.f;
}
__device__ __forceinline__ unsigned short f2bf(float f) {
  union { float f; unsigned v; } x;
  x.f = f;
  unsigned r = x.v + 0x7fffu + ((x.v >> 16) & 1u);
  return (unsigned short)(r >> 16);
}

// 8x f32 -> bf16x8 via v_cvt_pk_bf16_f32 (RNE, same as f2bf)
__device__ __forceinline__ bf16x8 cvt8(f32x4 a, f32x4 b) {
  union { unsigned u[4]; bf16x8 v; } r;
  asm("v_cvt_pk_bf16_f32 %0, %1, %2" : "=v"(r.u[0]) : "v"(a[0]), "v"(a[1]));
  asm("v_cvt_pk_bf16_f32 %0, %1, %2" : "=v"(r.u[1]) : "v"(a[2]), "v"(a[3]));
  asm("v_cvt_pk_bf16_f32 %0, %1, %2" : "=v"(r.u[2]) : "v"(b[0]), "v"(b[1]));
  asm("v_cvt_pk_bf16_f32 %0, %1, %2" : "=v"(r.u[3]) : "v"(b[2]), "v"(b[3]));
  return r.v;
}

// ---------------------------------------------------------------------------
// One-off weight preps (all tiny)
// ---------------------------------------------------------------------------
__global__ void convert_wt(const float* __restrict__ W,
                           unsigned short* __restrict__ Wt) {
  const int n = blockIdx.x, k = threadIdx.x;   // W is (256,256)
  Wt[n * 256 + k] = f2bf(W[k * 256 + n]);
}

// wcat[n][k], n<512: W_off, n<768: W_attn, n<896: Wa1, else 0
__global__ void build_wcat(const float* __restrict__ W_off,
                           const float* __restrict__ W_attn,
                           const float* __restrict__ Wa1,
                           unsigned short* __restrict__ wcat) {
  const int n = blockIdx.x, k = threadIdx.x;
  float v;
  if (n < 512) v = W_off[k * 512 + n];
  else if (n < 768) v = W_attn[k * 256 + (n - 512)];
  else if (n < 896) v = Wa1[k * 128 + (n - 768)];
  else v = 0.f;
  wcat[n * 256 + k] = f2bf(v);
}

__global__ void build_bcat(const float* __restrict__ b_off,
                           const float* __restrict__ b_attn,
                           const float* __restrict__ ba1,
                           float* __restrict__ bcat) {
  const int idx = blockIdx.x * 256 + threadIdx.x;
  float v;
  if (idx < 512) v = b_off[idx];
  else if (idx < 768) v = b_attn[idx - 512];
  else if (idx < 896) v = ba1[idx - 768];
  else v = 0.f;
  bcat[idx] = v;
}

// wa2t[n][k] = bf16(Wa2[k][n]), Wa2 is (128,512)
__global__ void build_wa2t(const float* __restrict__ Wa2,
                           unsigned short* __restrict__ wa2t) {
  const int n = blockIdx.x, k = threadIdx.x;
  wa2t[n * 128 + k] = f2bf(Wa2[k * 512 + n]);
}

// ---------------------------------------------------------------------------
// MFMA GEMM with async global_load_lds f32-A staging (m97-style).
// C[M, n_total] = A[M,256](f32) @ Wt^T + bias ; Wt bf16 [n][256].
// BM=128, BN=256 (grid.y tiles), BK=32 f32. 512 threads = 8 waves (2x4),
// wave tile 64x64 = 4x4 fragments. LDS: 2 x 128x32 f32 (16 KB each).
// Swizzle (rule: both-sides-or-neither): storage 16B-chunk c_s of row r holds
// logical chunk c_l = c_s ^ (r&7); DMA dest is linear, the lane's GLOBAL
// source is pre-swizzled; fragment reads XOR the same involution.
// ---------------------------------------------------------------------------
template <int OUT_BF16>
__global__ __launch_bounds__(512, 1) void gemm_vstage(
    const float* __restrict__ A, const unsigned short* __restrict__ Wt,
    const float* __restrict__ bias, void* __restrict__ Cout, int n_total) {
  __shared__ float As[2][128 * 32];
  const int tid = threadIdx.x;
  const int lane = tid & 63;
  const int wid = tid >> 6;          // 0..7
  const long bm = (long)blockIdx.x * 128;
  const int bn0 = blockIdx.y * 256;
  const int wr = wid >> 2, wc = wid & 3;
  const int rowc = lane & 15, rowg = lane >> 4;

  f32x4 acc[4][4];
#pragma unroll
  for (int m = 0; m < 4; ++m)
#pragma unroll
    for (int n = 0; n < 4; ++n) acc[m][n] = (f32x4){0.f, 0.f, 0.f, 0.f};

  // staging source precompute: issue i covers LDS bytes
  // [wid*1024 + i*8192 + lane*16, +16) of the buffer (linear DMA dest).
  // row = wid*8 + i*64 + (lane>>3); storage chunk c_s = lane&7;
  // fetch logical chunk c_l = c_s ^ (row&7) from global.
  const float* ssrc[2];
#pragma unroll
  for (int i = 0; i < 2; ++i) {
    const int row = wid * 8 + i * 64 + (lane >> 3);
    const int cl = (lane & 7) ^ (row & 7);
    ssrc[i] = A + (bm + row) * 256 + cl * 4;
  }

  auto stage = [&](int b, int ks) {
#pragma unroll
    for (int i = 0; i < 2; ++i) {
      const float* src = ssrc[i] + ks * 32;
      char* dst = (char*)&As[0][0] + b * 16384 + wid * 1024 + i * 8192;
      __builtin_amdgcn_global_load_lds(
          (const __attribute__((address_space(1))) void*)src,
          (__attribute__((address_space(3))) void*)dst, 16, 0, 0);
    }
  };

  stage(0, 0);
  __syncthreads();

  int cur = 0;
#pragma unroll
  for (int ks = 0; ks < 8; ++ks) {
    if (ks < 7) stage(cur ^ 1, ks + 1);
    // B fragments straight from L2-resident transposed weights
    bf16x8 bfrag[4];
#pragma unroll
    for (int n = 0; n < 4; ++n) {
      bfrag[n] = *(const bf16x8*)(
          Wt + (long)(bn0 + wc * 64 + n * 16 + rowc) * 256 + ks * 32 +
          rowg * 8);
    }
    // A fragments from swizzled LDS + in-reg cvt to bf16
    bf16x8 afrag[4];
#pragma unroll
    for (int m = 0; m < 4; ++m) {
      const int r = wr * 64 + m * 16 + rowc;
      const f32x4 x0 =
          *(const f32x4*)&As[cur][r * 32 + (((rowg << 1) | 0) ^ (r & 7)) * 4];
      const f32x4 x1 =
          *(const f32x4*)&As[cur][r * 32 + (((rowg << 1) | 1) ^ (r & 7)) * 4];
      afrag[m] = cvt8(x0, x1);
    }
#pragma unroll
    for (int m = 0; m < 4; ++m)
#pragma unroll
      for (int n = 0; n < 4; ++n)
        acc[m][n] = __builtin_amdgcn_mfma_f32_16x16x32_bf16(
            afrag[m], bfrag[n], acc[m][n], 0, 0, 0);
    __syncthreads();
    cur ^= 1;
  }

  // epilogue
#pragma unroll
  for (int m = 0; m < 4; ++m) {
#pragma unroll
    for (int n = 0; n < 4; ++n) {
      const int col = bn0 + wc * 64 + n * 16 + rowc;
      const float bb = bias[col];
#pragma unroll
      for (int j = 0; j < 4; ++j) {
        const long row = bm + wr * 64 + m * 16 + rowg * 4 + j;
        const float val = acc[m][n][j] + bb;
        if (OUT_BF16)
          ((unsigned short*)Cout)[row * n_total + col] = f2bf(val);
        else
          ((float*)Cout)[row * n_total + col] = val;
      }
    }
  }
}

// ---------------------------------------------------------------------------
// Reg-staged MFMA GEMM (kept for bf16-A off2): C = A[M,K_DIM]bf16 @ Wt^T + b
// ---------------------------------------------------------------------------
#define AS_STRIDE 40  // ushorts per LDS row (80 B -> only free 2-way aliasing)

template <int OUT_BF16, int A_BF16, int K_DIM>
__global__ __launch_bounds__(512, 1) void gemm_mfma(
    const void* __restrict__ Ain, const unsigned short* __restrict__ Wt,
    const float* __restrict__ bias, void* __restrict__ Cout, int n_total) {
  constexpr int KSTEPS = K_DIM / 32;
  __shared__ unsigned short As[2][128 * AS_STRIDE];
  const int tid = threadIdx.x;
  const long bm = (long)blockIdx.x * 128;
  const int bn0 = blockIdx.y * 256;
  const int lane = tid & 63;
  const int wid = tid >> 6;
  const int wr = wid >> 2;         // 0..1
  const int wc = wid & 3;          // 0..3
  const int rowg = (lane >> 4);    // 0..3
  const int rowc = lane & 15;      // 0..15

  const int srow = tid >> 2;       // 0..127
  const int skc = (tid & 3) * 8;   // 0,8,16,24

  f32x4 acc[4][4];
#pragma unroll
  for (int m = 0; m < 4; ++m)
#pragma unroll
    for (int n = 0; n < 4; ++n) acc[m][n] = (f32x4){0.f, 0.f, 0.f, 0.f};

  const float* srcf = (const float*)Ain + (bm + srow) * (long)K_DIM + skc;
  const unsigned short* srcb =
      (const unsigned short*)Ain + (bm + srow) * (long)K_DIM + skc;

  {
    ushort8 u;
    if constexpr (A_BF16) {
      u = *(const ushort8*)srcb;
    } else {
      float4 f0 = *(const float4*)(srcf + 0);
      float4 f1 = *(const float4*)(srcf + 4);
      u[0] = f2bf(f0.x); u[1] = f2bf(f0.y); u[2] = f2bf(f0.z); u[3] = f2bf(f0.w);
      u[4] = f2bf(f1.x); u[5] = f2bf(f1.y); u[6] = f2bf(f1.z); u[7] = f2bf(f1.w);
    }
    *(ushort8*)&As[0][srow * AS_STRIDE + skc] = u;
  }
  __syncthreads();

  int cur = 0;
#pragma unroll
  for (int ks = 0; ks < KSTEPS; ++ks) {
    ushort8 pre;
    if (ks < KSTEPS - 1) {
      if constexpr (A_BF16) {
        pre = *(const ushort8*)(srcb + (ks + 1) * 32);
      } else {
        float4 f0 = *(const float4*)(srcf + (ks + 1) * 32 + 0);
        float4 f1 = *(const float4*)(srcf + (ks + 1) * 32 + 4);
        pre[0] = f2bf(f0.x); pre[1] = f2bf(f0.y);
        pre[2] = f2bf(f0.z); pre[3] = f2bf(f0.w);
        pre[4] = f2bf(f1.x); pre[5] = f2bf(f1.y);
        pre[6] = f2bf(f1.z); pre[7] = f2bf(f1.w);
      }
    }
    bf16x8 bfrag[4];
#pragma unroll
    for (int n = 0; n < 4; ++n) {
      const unsigned short* wp =
          Wt + (long)(bn0 + wc * 64 + n * 16 + rowc) * K_DIM + ks * 32 +
          rowg * 8;
      bfrag[n] = *(const bf16x8*)wp;
    }
    bf16x8 afrag[4];
#pragma unroll
    for (int m = 0; m < 4; ++m) {
      const int r = wr * 64 + m * 16 + rowc;
      afrag[m] = *(const bf16x8*)&As[cur][r * AS_STRIDE + rowg * 8];
    }
#pragma unroll
    for (int m = 0; m < 4; ++m)
#pragma unroll
      for (int n = 0; n < 4; ++n)
        acc[m][n] = __builtin_amdgcn_mfma_f32_16x16x32_bf16(
            afrag[m], bfrag[n], acc[m][n], 0, 0, 0);

    if (ks < KSTEPS - 1) {
      *(ushort8*)&As[cur ^ 1][srow * AS_STRIDE + skc] = pre;
    }
    __syncthreads();
    cur ^= 1;
  }

#pragma unroll
  for (int m = 0; m < 4; ++m) {
#pragma unroll
    for (int n = 0; n < 4; ++n) {
      const int col = bn0 + wc * 64 + n * 16 + rowc;
      const float bb = bias[col];
#pragma unroll
      for (int j = 0; j < 4; ++j) {
        const long row = bm + wr * 64 + m * 16 + rowg * 4 + j;
        const float val = acc[m][n][j] + bb;
        if (OUT_BF16)
          ((unsigned short*)Cout)[row * n_total + col] = f2bf(val);
        else
          ((float*)Cout)[row * n_total + col] = val;
      }
    }
  }
}

// ---------------------------------------------------------------------------
// hidb = bf16(relu(proj[:, 768:896]))
// ---------------------------------------------------------------------------
__global__ __launch_bounds__(256) void relu_hid(const float* __restrict__ proj,
                                                unsigned short* __restrict__ hidb) {
  const int idx = blockIdx.x * 256 + threadIdx.x;  // < 8192*128
  const int q = idx >> 7, j = idx & 127;
  hidb[idx] = f2bf(fmaxf(proj[(long)q * 1024 + 768 + j], 0.f));
}

// ---------------------------------------------------------------------------
// finalize: grid coords + softmax attention weights.
// One block = 16 queries, 256 threads.
// ---------------------------------------------------------------------------
__global__ __launch_bounds__(256) void finalize_qproj(
    const float* __restrict__ proj, const float* __restrict__ off2,
    const float* __restrict__ refpts, float* __restrict__ grid_out,
    float* __restrict__ aw_out) {
  const int tid = threadIdx.x;
  const long q0 = (long)blockIdx.x * 16;
#pragma unroll 4
  for (int q = 0; q < 16; ++q) {
    const long qi = q0 + q;
    const float* pr = proj + qi * 1024;
    float logit = pr[512 + tid];
    float m = logit;
#pragma unroll
    for (int mask = 16; mask > 0; mask >>= 1)
      m = fmaxf(m, __shfl_xor(m, mask));
    float e = __expf(logit - m);
    float s = e;
#pragma unroll
    for (int mask = 16; mask > 0; mask >>= 1) s += __shfl_xor(s, mask);
    aw_out[qi * 256 + tid] = e / s;
#pragma unroll
    for (int half = 0; half < 2; ++half) {
      const int o = tid + half * 256;
      const float offv = pr[o] + 0.1f * off2[qi * 512 + o];
      const int l = (o >> 4) & 3;
      const int c = o & 1;
      const float rnorm = 1.f / (float)(128 >> l);
      const float ref = refpts[qi * 8 + l * 2 + c];
      grid_out[qi * 512 + o] = (ref + offv * rnorm) * 2.f - 1.f;
    }
  }
}

// ---------------------------------------------------------------------------
// Bilinear sampling + attention-weighted accumulation. v is bf16.
// Block = 2 queries, 256 threads. Phase 1: 512 samples -> corner offsets +
// fused weights in LDS. Phase 2: thread = (query, head, channel-pair).
// ---------------------------------------------------------------------------
__global__ __launch_bounds__(256) void sample_kernel(
    const unsigned short* __restrict__ v, const float* __restrict__ grid,
    const float* __restrict__ aw, float* __restrict__ acc_out) {
  __shared__ int4 sidx[512];
  __shared__ float4 sw[512];
  const int tid = threadIdx.x;
  const long q0 = (long)blockIdx.x * 2;
  const int b = (int)(q0 >> 11);
  constexpr int starts[4] = {0, 16384, 20480, 21504};

#pragma unroll
  for (int ss = 0; ss < 2; ++ss) {
    const int s = tid + ss * 256;
    const int qq = s >> 8, j = s & 255;       // j = h*32 + l*8 + p
    const int l = (j >> 3) & 3;
    const int HW = 128 >> l;
    const float fHW = (float)HW;
    const float2 g = *(const float2*)(grid + (q0 + qq) * 512 + 2 * j);
    const float w = aw[(q0 + qq) * 256 + j];
    const float x = ((g.x + 1.f) * fHW - 1.f) * 0.5f;
    const float y = ((g.y + 1.f) * fHW - 1.f) * 0.5f;
    const float x0f = floorf(x), y0f = floorf(y);
    const float lx = x - x0f, ly = y - y0f;
    const int ix0 = (int)x0f, iy0 = (int)y0f;
    const int ix1 = ix0 + 1, iy1 = iy0 + 1;
    const float vx0 = (ix0 >= 0 && ix0 < HW) ? 1.f : 0.f;
    const float vx1 = (ix1 >= 0 && ix1 < HW) ? 1.f : 0.f;
    const float vy0 = (iy0 >= 0 && iy0 < HW) ? 1.f : 0.f;
    const float vy1 = (iy1 >= 0 && iy1 < HW) ? 1.f : 0.f;
    const int cx0 = min(max(ix0, 0), HW - 1);
    const int cx1 = min(max(ix1, 0), HW - 1);
    const int cy0 = min(max(iy0, 0), HW - 1);
    const int cy1 = min(max(iy1, 0), HW - 1);
    const int base = starts[l];
    int4 o;  // byte offsets into v (256 ch * 2 B per location)
    o.x = (base + cy0 * HW + cx0) * 512;
    o.y = (base + cy0 * HW + cx1) * 512;
    o.z = (base + cy1 * HW + cx0) * 512;
    o.w = (base + cy1 * HW + cx1) * 512;
    sidx[s] = o;
    float4 wv;
    wv.x = (1.f - lx) * (1.f - ly) * vx0 * vy0 * w;
    wv.y = lx * (1.f - ly) * vx1 * vy0 * w;
    wv.z = (1.f - lx) * ly * vx0 * vy1 * w;
    wv.w = lx * ly * vx1 * vy1 * w;
    sw[s] = wv;
  }
  __syncthreads();

  const int qq = tid >> 7, h = (tid >> 4) & 7, dp = tid & 15;
  const char* vb =
      (const char*)v + ((long)b * LV_SZ * 256 + h * 32 + dp * 2) * 2;
  const int sbase = qq * 256 + h * 32;
  float acc0 = 0.f, acc1 = 0.f;
#pragma unroll 8
  for (int j = 0; j < 32; ++j) {
    const int4 o = sidx[sbase + j];
    const float4 w = sw[sbase + j];
    const ushort2 u0 = *(const ushort2*)(vb + o.x);
    const ushort2 u1 = *(const ushort2*)(vb + o.y);
    const ushort2 u2 = *(const ushort2*)(vb + o.z);
    const ushort2 u3 = *(const ushort2*)(vb + o.w);
    acc0 = fmaf(bf2f(u0.x), w.x, acc0);
    acc1 = fmaf(bf2f(u0.y), w.x, acc1);
    acc0 = fmaf(bf2f(u1.x), w.y, acc0);
    acc1 = fmaf(bf2f(u1.y), w.y, acc1);
    acc0 = fmaf(bf2f(u2.x), w.z, acc0);
    acc1 = fmaf(bf2f(u2.y), w.z, acc1);
    acc0 = fmaf(bf2f(u3.x), w.w, acc0);
    acc1 = fmaf(bf2f(u3.y), w.w, acc1);
  }
  float2 res = {acc0, acc1};
  *(float2*)(acc_out + (q0 + qq) * 256 + h * 32 + dp * 2) = res;
}

// ---------------------------------------------------------------------------
extern "C" void kernel_launch(void* const* d_in, const int* in_sizes, int n_in,
                              void* d_out, int out_size, void* d_ws,
                              size_t ws_size, hipStream_t stream) {
  const float* query  = (const float*)d_in[0];
  const float* refpts = (const float*)d_in[1];
  const float* value  = (const float*)d_in[2];
  const float* W_off  = (const float*)d_in[5];
  const float* b_off  = (const float*)d_in[6];
  const float* W_attn = (const float*)d_in[7];
  const float* b_attn = (const float*)d_in[8];
  const float* Wa1    = (const float*)d_in[9];
  const float* ba1    = (const float*)d_in[10];
  const float* Wa2    = (const float*)d_in[11];
  const float* ba2    = (const float*)d_in[12];
  const float* Wv     = (const float*)d_in[13];
  const float* bv     = (const float*)d_in[14];
  const float* Wo     = (const float*)d_in[15];
  const float* bo     = (const float*)d_in[16];
  float* out = (float*)d_out;

  char* ws = (char*)d_ws;
  // layout (total 122,556,416 B):
  unsigned short* v_ws = (unsigned short*)ws;                   // 44,564,480
  float* proj_ws = (float*)(ws + 44564480);                     // 33,554,432
  float* acc_ws  = (float*)(ws + 44564480);        // aliases proj (dead then)
  float* off2_ws = (float*)(ws + 78118912);                     // 16,777,216
  unsigned short* wcat_ws = (unsigned short*)(ws + 78118912);   // aliases off2
  unsigned short* hidb_ws = (unsigned short*)(ws + 94896128);   //  2,097,152
  float* grid_ws = (float*)(ws + 96993280);                     // 16,777,216
  float* aw_ws   = (float*)(ws + 113770496);                    //  8,388,608
  unsigned short* wtv_ws  = (unsigned short*)(ws + 122159104);  //    131,072
  unsigned short* wto_ws  = (unsigned short*)(ws + 122290176);  //    131,072
  unsigned short* wa2t_ws = (unsigned short*)(ws + 122421248);  //    131,072
  float* bcat_ws = (float*)(ws + 122552320);                    //      4,096

  // 0) weight preps
  convert_wt<<<256, 256, 0, stream>>>(Wv, wtv_ws);
  convert_wt<<<256, 256, 0, stream>>>(Wo, wto_ws);
  build_wcat<<<1024, 256, 0, stream>>>(W_off, W_attn, Wa1, wcat_ws);
  build_bcat<<<4, 256, 0, stream>>>(b_off, b_attn, ba1, bcat_ws);
  build_wa2t<<<512, 128, 0, stream>>>(Wa2, wa2t_ws);
  // 1) v = value @ Wv + bv  (bf16 out)
  gemm_vstage<1><<<dim3(MV_SZ / 128, 1), 512, 0, stream>>>(
      value, wtv_ws, bv, v_ws, 256);
  // 2) proj = query @ [W_off|W_attn|Wa1|0] + bcat
  gemm_vstage<0><<<dim3(NQ_SZ / 128, 4), 512, 0, stream>>>(
      query, wcat_ws, bcat_ws, proj_ws, 1024);
  // 3) hidb = bf16(relu(proj[:,768:896]))
  relu_hid<<<NQ_SZ * 128 / 256, 256, 0, stream>>>(proj_ws, hidb_ws);
  // 4) off2 = hidb @ Wa2 + ba2
  gemm_mfma<0, 1, 128><<<dim3(NQ_SZ / 128, 2), 512, 0, stream>>>(
      hidb_ws, wa2t_ws, ba2, off2_ws, 512);
  // 5) grids + attention weights
  finalize_qproj<<<NQ_SZ / 16, 256, 0, stream>>>(proj_ws, off2_ws, refpts,
                                                 grid_ws, aw_ws);
  // 6) bilinear sampling + weighted accumulation
  sample_kernel<<<NQ_SZ / 2, 256, 0, stream>>>(v_ws, grid_ws, aw_ws, acc_ws);
  // 7) out = acc @ Wo + bo
  gemm_vstage<0><<<dim3(NQ_SZ / 128, 1), 512, 0, stream>>>(
      acc_ws, wto_ws, bo, out, 256);
}

// Round 8
// 150.866 us; speedup vs baseline: 1.2959x; 1.0367x over previous
//
#include <hip/hip_runtime.h>
#include <math.h>

#define B_SZ 4
#define LQ_SZ 2048
#define C_SZ 256
#define NH_SZ 8
#define NL_SZ 4
#define NP_SZ 8
#define HD_SZ 32
#define LV_SZ 21760
#define NQ_SZ (B_SZ * LQ_SZ)   // 8192
#define MV_SZ (B_SZ * LV_SZ)   // 87040

typedef __attribute__((ext_vector_type(8))) short bf16x8;
typedef __attribute__((ext_vector_type(8))) unsigned short ushort8;
typedef __attribute__((ext_vector_type(4))) float f32x4;

__device__ __forceinline__ float bf2f(unsigned short u) {
  union { float f; unsigned v; } x;
  x.v = ((unsigned)u) << 16;
  return x.f;
}
__device__ __forceinline__ unsigned short f2bf(float f) {
  union { float f; unsigned v; } x;
  x.f = f;
  unsigned r = x.v + 0x7fffu + ((x.v >> 16) & 1u);
  return (unsigned short)(r >> 16);
}

// 8x f32 -> bf16x8 via v_cvt_pk_bf16_f32 (RNE, same as f2bf)
__device__ __forceinline__ bf16x8 cvt8(f32x4 a, f32x4 b) {
  union { unsigned u[4]; bf16x8 v; } r;
  asm("v_cvt_pk_bf16_f32 %0, %1, %2" : "=v"(r.u[0]) : "v"(a[0]), "v"(a[1]));
  asm("v_cvt_pk_bf16_f32 %0, %1, %2" : "=v"(r.u[1]) : "v"(a[2]), "v"(a[3]));
  asm("v_cvt_pk_bf16_f32 %0, %1, %2" : "=v"(r.u[2]) : "v"(b[0]), "v"(b[1]));
  asm("v_cvt_pk_bf16_f32 %0, %1, %2" : "=v"(r.u[3]) : "v"(b[2]), "v"(b[3]));
  return r.v;
}

// ---------------------------------------------------------------------------
// One-off weight preps (all tiny)
// ---------------------------------------------------------------------------
__global__ void convert_wt(const float* __restrict__ W,
                           unsigned short* __restrict__ Wt) {
  const int n = blockIdx.x, k = threadIdx.x;   // W is (256,256)
  Wt[n * 256 + k] = f2bf(W[k * 256 + n]);
}

// wcat[n][k], n<512: W_off, n<768: W_attn, n<896: Wa1, else 0
__global__ void build_wcat(const float* __restrict__ W_off,
                           const float* __restrict__ W_attn,
                           const float* __restrict__ Wa1,
                           unsigned short* __restrict__ wcat) {
  const int n = blockIdx.x, k = threadIdx.x;
  float v;
  if (n < 512) v = W_off[k * 512 + n];
  else if (n < 768) v = W_attn[k * 256 + (n - 512)];
  else if (n < 896) v = Wa1[k * 128 + (n - 768)];
  else v = 0.f;
  wcat[n * 256 + k] = f2bf(v);
}

__global__ void build_bcat(const float* __restrict__ b_off,
                           const float* __restrict__ b_attn,
                           const float* __restrict__ ba1,
                           float* __restrict__ bcat) {
  const int idx = blockIdx.x * 256 + threadIdx.x;
  float v;
  if (idx < 512) v = b_off[idx];
  else if (idx < 768) v = b_attn[idx - 512];
  else if (idx < 896) v = ba1[idx - 768];
  else v = 0.f;
  bcat[idx] = v;
}

// wa2t[n][k] = bf16(Wa2[k][n]), Wa2 is (128,512)
__global__ void build_wa2t(const float* __restrict__ Wa2,
                           unsigned short* __restrict__ wa2t) {
  const int n = blockIdx.x, k = threadIdx.x;
  wa2t[n * 128 + k] = f2bf(Wa2[k * 512 + n]);
}

// ---------------------------------------------------------------------------
// Deep-pipelined MFMA GEMM: C[M,n_total] = A[M,256](f32) @ Wt^T + bias.
// Wt bf16 [n][256]. BM=64, BN=256 (grid.y tiles), BK=32. 256 threads =
// 4 col-waves, each 64(rows) x 64(cols) = 4x4 fragments.
// BOTH A and B staged via global_load_lds into a 3-buffer ring; the K-loop
// contains NO other global loads, so counted s_waitcnt vmcnt(N) (never 0
// mid-loop) keeps 2-3 stages in flight across raw s_barriers (T3+T4).
// Per buffer (24 KB): A = 64x32 f32 (8 KB, XOR-swizzled 16B chunks:
// stored chunk c_s holds logical c_s^(row&7)); B = 4 k-chunks x 256 cols
// x 16B (16 KB, chunk-major -> conflict-free ds_read_b128).
// ---------------------------------------------------------------------------
template <int OUT_BF16>
__global__ void gemm_pipe(const float* __restrict__ A,
                          const unsigned short* __restrict__ Wt,
                          const float* __restrict__ bias,
                          void* __restrict__ Cout, int n_total) {
  __shared__ __align__(16) char lds[3][24576];
  const int tid = threadIdx.x;
  const int lane = tid & 63;
  const int wid = tid >> 6;              // 0..3 == col-wave wc
  const long bm = (long)blockIdx.x * 64;
  const int bn0 = blockIdx.y * 256;
  const int rowc = lane & 15, rowg = lane >> 4;

  f32x4 acc[4][4];
#pragma unroll
  for (int m = 0; m < 4; ++m)
#pragma unroll
    for (int n = 0; n < 4; ++n) acc[m][n] = (f32x4){0.f, 0.f, 0.f, 0.f};

  // A staging: issue i in {0,1}; LDS off = i*4096 + wid*1024 (+ lane*16 HW).
  // row = i*32 + wid*8 + lane>>3, stored chunk c_s = lane&7 -> fetch logical
  // chunk c_s ^ (row&7) from global.
  const float* asrc[2];
#pragma unroll
  for (int i = 0; i < 2; ++i) {
    const int row = i * 32 + wid * 8 + (lane >> 3);
    const int cl = (lane & 7) ^ (row & 7);
    asrc[i] = A + (bm + row) * 256 + cl * 4;
  }
  // B staging: issue i in {0..3}; LDS off = 8192 + i*4096 + wid*1024
  // (+ lane*16); (k-chunk i, col = wid*64+lane).
  const unsigned short* bsrc[4];
#pragma unroll
  for (int i = 0; i < 4; ++i)
    bsrc[i] = Wt + (long)(bn0 + wid * 64 + lane) * 256 + i * 8;

  auto stage = [&](int buf, int ks) {
#pragma unroll
    for (int i = 0; i < 2; ++i)
      __builtin_amdgcn_global_load_lds(
          (const __attribute__((address_space(1))) void*)(asrc[i] + ks * 32),
          (__attribute__((address_space(3))) void*)(
              &lds[buf][i * 4096 + wid * 1024]),
          16, 0, 0);
#pragma unroll
    for (int i = 0; i < 4; ++i)
      __builtin_amdgcn_global_load_lds(
          (const __attribute__((address_space(1))) void*)(bsrc[i] + ks * 32),
          (__attribute__((address_space(3))) void*)(
              &lds[buf][8192 + i * 4096 + wid * 1024]),
          16, 0, 0);
  };

  stage(0, 0);
  stage(1, 1);
  stage(2, 2);   // 18 loads/thread outstanding (6 per stage)

#pragma unroll
  for (int ks = 0; ks < 8; ++ks) {
    // wait for stage ks only; keep younger stages in flight
    if (ks <= 5)
      asm volatile("s_waitcnt vmcnt(12)" ::: "memory");
    else if (ks == 6)
      asm volatile("s_waitcnt vmcnt(6)" ::: "memory");
    else
      asm volatile("s_waitcnt vmcnt(0)" ::: "memory");
    __builtin_amdgcn_s_barrier();

    const char* buf = lds[ks % 3];
    bf16x8 bfrag[4];
#pragma unroll
    for (int n = 0; n < 4; ++n) {
      const int col = wid * 64 + n * 16 + rowc;
      bfrag[n] = *(const bf16x8*)(buf + 8192 + rowg * 4096 + col * 16);
    }
    bf16x8 afrag[4];
#pragma unroll
    for (int m = 0; m < 4; ++m) {
      const int r = m * 16 + rowc;
      const f32x4 x0 =
          *(const f32x4*)(buf + r * 128 + (((rowg << 1) | 0) ^ (r & 7)) * 16);
      const f32x4 x1 =
          *(const f32x4*)(buf + r * 128 + (((rowg << 1) | 1) ^ (r & 7)) * 16);
      afrag[m] = cvt8(x0, x1);
    }
#pragma unroll
    for (int m = 0; m < 4; ++m)
#pragma unroll
      for (int n = 0; n < 4; ++n)
        acc[m][n] = __builtin_amdgcn_mfma_f32_16x16x32_bf16(
            afrag[m], bfrag[n], acc[m][n], 0, 0, 0);

    asm volatile("s_waitcnt lgkmcnt(0)" ::: "memory");
    __builtin_amdgcn_s_barrier();
    if (ks < 5) stage(ks % 3, ks + 3);  // overwrite just-consumed buffer
  }

  // epilogue
#pragma unroll
  for (int m = 0; m < 4; ++m) {
#pragma unroll
    for (int n = 0; n < 4; ++n) {
      const int col = bn0 + wid * 64 + n * 16 + rowc;
      const float bb = bias[col];
#pragma unroll
      for (int j = 0; j < 4; ++j) {
        const long row = bm + m * 16 + rowg * 4 + j;
        const float val = acc[m][n][j] + bb;
        if (OUT_BF16)
          ((unsigned short*)Cout)[row * n_total + col] = f2bf(val);
        else
          ((float*)Cout)[row * n_total + col] = val;
      }
    }
  }
}

// ---------------------------------------------------------------------------
// Reg-staged MFMA GEMM (kept for bf16-A off2): C = A[M,K_DIM]bf16 @ Wt^T + b
// ---------------------------------------------------------------------------
#define AS_STRIDE 40  // ushorts per LDS row (80 B -> only free 2-way aliasing)

template <int OUT_BF16, int A_BF16, int K_DIM>
__global__ __launch_bounds__(512, 1) void gemm_mfma(
    const void* __restrict__ Ain, const unsigned short* __restrict__ Wt,
    const float* __restrict__ bias, void* __restrict__ Cout, int n_total) {
  constexpr int KSTEPS = K_DIM / 32;
  __shared__ unsigned short As[2][128 * AS_STRIDE];
  const int tid = threadIdx.x;
  const long bm = (long)blockIdx.x * 128;
  const int bn0 = blockIdx.y * 256;
  const int lane = tid & 63;
  const int wid = tid >> 6;
  const int wr = wid >> 2;
  const int wc = wid & 3;
  const int rowg = (lane >> 4);
  const int rowc = lane & 15;

  const int srow = tid >> 2;
  const int skc = (tid & 3) * 8;

  f32x4 acc[4][4];
#pragma unroll
  for (int m = 0; m < 4; ++m)
#pragma unroll
    for (int n = 0; n < 4; ++n) acc[m][n] = (f32x4){0.f, 0.f, 0.f, 0.f};

  const unsigned short* srcb =
      (const unsigned short*)Ain + (bm + srow) * (long)K_DIM + skc;

  {
    ushort8 u = *(const ushort8*)srcb;
    *(ushort8*)&As[0][srow * AS_STRIDE + skc] = u;
  }
  __syncthreads();

  int cur = 0;
#pragma unroll
  for (int ks = 0; ks < KSTEPS; ++ks) {
    ushort8 pre;
    if (ks < KSTEPS - 1) pre = *(const ushort8*)(srcb + (ks + 1) * 32);
    bf16x8 bfrag[4];
#pragma unroll
    for (int n = 0; n < 4; ++n) {
      const unsigned short* wp =
          Wt + (long)(bn0 + wc * 64 + n * 16 + rowc) * K_DIM + ks * 32 +
          rowg * 8;
      bfrag[n] = *(const bf16x8*)wp;
    }
    bf16x8 afrag[4];
#pragma unroll
    for (int m = 0; m < 4; ++m) {
      const int r = wr * 64 + m * 16 + rowc;
      afrag[m] = *(const bf16x8*)&As[cur][r * AS_STRIDE + rowg * 8];
    }
#pragma unroll
    for (int m = 0; m < 4; ++m)
#pragma unroll
      for (int n = 0; n < 4; ++n)
        acc[m][n] = __builtin_amdgcn_mfma_f32_16x16x32_bf16(
            afrag[m], bfrag[n], acc[m][n], 0, 0, 0);

    if (ks < KSTEPS - 1) {
      *(ushort8*)&As[cur ^ 1][srow * AS_STRIDE + skc] = pre;
    }
    __syncthreads();
    cur ^= 1;
  }

#pragma unroll
  for (int m = 0; m < 4; ++m) {
#pragma unroll
    for (int n = 0; n < 4; ++n) {
      const int col = bn0 + wc * 64 + n * 16 + rowc;
      const float bb = bias[col];
#pragma unroll
      for (int j = 0; j < 4; ++j) {
        const long row = bm + wr * 64 + m * 16 + rowg * 4 + j;
        const float val = acc[m][n][j] + bb;
        if (OUT_BF16)
          ((unsigned short*)Cout)[row * n_total + col] = f2bf(val);
        else
          ((float*)Cout)[row * n_total + col] = val;
      }
    }
  }
}

// ---------------------------------------------------------------------------
// hidb = bf16(relu(proj[:, 768:896]))
// ---------------------------------------------------------------------------
__global__ __launch_bounds__(256) void relu_hid(const float* __restrict__ proj,
                                                unsigned short* __restrict__ hidb) {
  const int idx = blockIdx.x * 256 + threadIdx.x;  // < 8192*128
  const int q = idx >> 7, j = idx & 127;
  hidb[idx] = f2bf(fmaxf(proj[(long)q * 1024 + 768 + j], 0.f));
}

// ---------------------------------------------------------------------------
// finalize: grid coords + softmax attention weights.
// ---------------------------------------------------------------------------
__global__ __launch_bounds__(256) void finalize_qproj(
    const float* __restrict__ proj, const float* __restrict__ off2,
    const float* __restrict__ refpts, float* __restrict__ grid_out,
    float* __restrict__ aw_out) {
  const int tid = threadIdx.x;
  const long q0 = (long)blockIdx.x * 16;
#pragma unroll 4
  for (int q = 0; q < 16; ++q) {
    const long qi = q0 + q;
    const float* pr = proj + qi * 1024;
    float logit = pr[512 + tid];
    float m = logit;
#pragma unroll
    for (int mask = 16; mask > 0; mask >>= 1)
      m = fmaxf(m, __shfl_xor(m, mask));
    float e = __expf(logit - m);
    float s = e;
#pragma unroll
    for (int mask = 16; mask > 0; mask >>= 1) s += __shfl_xor(s, mask);
    aw_out[qi * 256 + tid] = e / s;
#pragma unroll
    for (int half = 0; half < 2; ++half) {
      const int o = tid + half * 256;
      const float offv = pr[o] + 0.1f * off2[qi * 512 + o];
      const int l = (o >> 4) & 3;
      const int c = o & 1;
      const float rnorm = 1.f / (float)(128 >> l);
      const float ref = refpts[qi * 8 + l * 2 + c];
      grid_out[qi * 512 + o] = (ref + offv * rnorm) * 2.f - 1.f;
    }
  }
}

// ---------------------------------------------------------------------------
// Bilinear sampling + attention-weighted accumulation. v is bf16.
// ---------------------------------------------------------------------------
__global__ __launch_bounds__(256) void sample_kernel(
    const unsigned short* __restrict__ v, const float* __restrict__ grid,
    const float* __restrict__ aw, float* __restrict__ acc_out) {
  __shared__ int4 sidx[512];
  __shared__ float4 sw[512];
  const int tid = threadIdx.x;
  const long q0 = (long)blockIdx.x * 2;
  const int b = (int)(q0 >> 11);
  constexpr int starts[4] = {0, 16384, 20480, 21504};

#pragma unroll
  for (int ss = 0; ss < 2; ++ss) {
    const int s = tid + ss * 256;
    const int qq = s >> 8, j = s & 255;       // j = h*32 + l*8 + p
    const int l = (j >> 3) & 3;
    const int HW = 128 >> l;
    const float fHW = (float)HW;
    const float2 g = *(const float2*)(grid + (q0 + qq) * 512 + 2 * j);
    const float w = aw[(q0 + qq) * 256 + j];
    const float x = ((g.x + 1.f) * fHW - 1.f) * 0.5f;
    const float y = ((g.y + 1.f) * fHW - 1.f) * 0.5f;
    const float x0f = floorf(x), y0f = floorf(y);
    const float lx = x - x0f, ly = y - y0f;
    const int ix0 = (int)x0f, iy0 = (int)y0f;
    const int ix1 = ix0 + 1, iy1 = iy0 + 1;
    const float vx0 = (ix0 >= 0 && ix0 < HW) ? 1.f : 0.f;
    const float vx1 = (ix1 >= 0 && ix1 < HW) ? 1.f : 0.f;
    const float vy0 = (iy0 >= 0 && iy0 < HW) ? 1.f : 0.f;
    const float vy1 = (iy1 >= 0 && iy1 < HW) ? 1.f : 0.f;
    const int cx0 = min(max(ix0, 0), HW - 1);
    const int cx1 = min(max(ix1, 0), HW - 1);
    const int cy0 = min(max(iy0, 0), HW - 1);
    const int cy1 = min(max(iy1, 0), HW - 1);
    const int base = starts[l];
    int4 o;  // byte offsets into v (256 ch * 2 B per location)
    o.x = (base + cy0 * HW + cx0) * 512;
    o.y = (base + cy0 * HW + cx1) * 512;
    o.z = (base + cy1 * HW + cx0) * 512;
    o.w = (base + cy1 * HW + cx1) * 512;
    sidx[s] = o;
    float4 wv;
    wv.x = (1.f - lx) * (1.f - ly) * vx0 * vy0 * w;
    wv.y = lx * (1.f - ly) * vx1 * vy0 * w;
    wv.z = (1.f - lx) * ly * vx0 * vy1 * w;
    wv.w = lx * ly * vx1 * vy1 * w;
    sw[s] = wv;
  }
  __syncthreads();

  const int qq = tid >> 7, h = (tid >> 4) & 7, dp = tid & 15;
  const char* vb =
      (const char*)v + ((long)b * LV_SZ * 256 + h * 32 + dp * 2) * 2;
  const int sbase = qq * 256 + h * 32;
  float acc0 = 0.f, acc1 = 0.f;
#pragma unroll 8
  for (int j = 0; j < 32; ++j) {
    const int4 o = sidx[sbase + j];
    const float4 w = sw[sbase + j];
    const ushort2 u0 = *(const ushort2*)(vb + o.x);
    const ushort2 u1 = *(const ushort2*)(vb + o.y);
    const ushort2 u2 = *(const ushort2*)(vb + o.z);
    const ushort2 u3 = *(const ushort2*)(vb + o.w);
    acc0 = fmaf(bf2f(u0.x), w.x, acc0);
    acc1 = fmaf(bf2f(u0.y), w.x, acc1);
    acc0 = fmaf(bf2f(u1.x), w.y, acc0);
    acc1 = fmaf(bf2f(u1.y), w.y, acc1);
    acc0 = fmaf(bf2f(u2.x), w.z, acc0);
    acc1 = fmaf(bf2f(u2.y), w.z, acc1);
    acc0 = fmaf(bf2f(u3.x), w.w, acc0);
    acc1 = fmaf(bf2f(u3.y), w.w, acc1);
  }
  float2 res = {acc0, acc1};
  *(float2*)(acc_out + (q0 + qq) * 256 + h * 32 + dp * 2) = res;
}

// ---------------------------------------------------------------------------
extern "C" void kernel_launch(void* const* d_in, const int* in_sizes, int n_in,
                              void* d_out, int out_size, void* d_ws,
                              size_t ws_size, hipStream_t stream) {
  const float* query  = (const float*)d_in[0];
  const float* refpts = (const float*)d_in[1];
  const float* value  = (const float*)d_in[2];
  const float* W_off  = (const float*)d_in[5];
  const float* b_off  = (const float*)d_in[6];
  const float* W_attn = (const float*)d_in[7];
  const float* b_attn = (const float*)d_in[8];
  const float* Wa1    = (const float*)d_in[9];
  const float* ba1    = (const float*)d_in[10];
  const float* Wa2    = (const float*)d_in[11];
  const float* ba2    = (const float*)d_in[12];
  const float* Wv     = (const float*)d_in[13];
  const float* bv     = (const float*)d_in[14];
  const float* Wo     = (const float*)d_in[15];
  const float* bo     = (const float*)d_in[16];
  float* out = (float*)d_out;

  char* ws = (char*)d_ws;
  // layout (total 122,556,416 B):
  unsigned short* v_ws = (unsigned short*)ws;                   // 44,564,480
  float* proj_ws = (float*)(ws + 44564480);                     // 33,554,432
  float* acc_ws  = (float*)(ws + 44564480);        // aliases proj (dead then)
  float* off2_ws = (float*)(ws + 78118912);                     // 16,777,216
  unsigned short* wcat_ws = (unsigned short*)(ws + 78118912);   // aliases off2
  unsigned short* hidb_ws = (unsigned short*)(ws + 94896128);   //  2,097,152
  float* grid_ws = (float*)(ws + 96993280);                     // 16,777,216
  float* aw_ws   = (float*)(ws + 113770496);                    //  8,388,608
  unsigned short* wtv_ws  = (unsigned short*)(ws + 122159104);  //    131,072
  unsigned short* wto_ws  = (unsigned short*)(ws + 122290176);  //    131,072
  unsigned short* wa2t_ws = (unsigned short*)(ws + 122421248);  //    131,072
  float* bcat_ws = (float*)(ws + 122552320);                    //      4,096

  // 0) weight preps
  convert_wt<<<256, 256, 0, stream>>>(Wv, wtv_ws);
  convert_wt<<<256, 256, 0, stream>>>(Wo, wto_ws);
  build_wcat<<<1024, 256, 0, stream>>>(W_off, W_attn, Wa1, wcat_ws);
  build_bcat<<<4, 256, 0, stream>>>(b_off, b_attn, ba1, bcat_ws);
  build_wa2t<<<512, 128, 0, stream>>>(Wa2, wa2t_ws);
  // 1) v = value @ Wv + bv  (bf16 out)
  gemm_pipe<1><<<dim3(MV_SZ / 64, 1), 256, 0, stream>>>(
      value, wtv_ws, bv, v_ws, 256);
  // 2) proj = query @ [W_off|W_attn|Wa1|0] + bcat
  gemm_pipe<0><<<dim3(NQ_SZ / 64, 4), 256, 0, stream>>>(
      query, wcat_ws, bcat_ws, proj_ws, 1024);
  // 3) hidb = bf16(relu(proj[:,768:896]))
  relu_hid<<<NQ_SZ * 128 / 256, 256, 0, stream>>>(proj_ws, hidb_ws);
  // 4) off2 = hidb @ Wa2 + ba2
  gemm_mfma<0, 1, 128><<<dim3(NQ_SZ / 128, 2), 512, 0, stream>>>(
      hidb_ws, wa2t_ws, ba2, off2_ws, 512);
  // 5) grids + attention weights
  finalize_qproj<<<NQ_SZ / 16, 256, 0, stream>>>(proj_ws, off2_ws, refpts,
                                                 grid_ws, aw_ws);
  // 6) bilinear sampling + weighted accumulation
  sample_kernel<<<NQ_SZ / 2, 256, 0, stream>>>(v_ws, grid_ws, aw_ws, acc_ws);
  // 7) out = acc @ Wo + bo
  gemm_pipe<0><<<dim3(NQ_SZ / 64, 1), 256, 0, stream>>>(
      acc_ws, wto_ws, bo, out, 256);
}